// Round 7
// baseline (260.219 us; speedup 1.0000x reference)
//
#include <hip/hip_runtime.h>
#include <math.h>

#define NB        50            // n_boundaries
#define ED        50            // EMBD_DIM
#define OD        50            // OUT_DIM
#define HID       101           // MLP width
#define K         129           // dist samples per bucket (128 intervals)
#define NBUCKET   49            // in-range buckets (idx in [1,49])
#define NSAMP     (NBUCKET * K) // 6321 table rows (OOB handled via LDS)
#define ROWSTRIDE 52            // halves per row, 104 B = dword-aligned
#define NP        (16 * 65536)  // B*N points
#define CHUNK     17            // samples per build block
#define NCHUNK    8             // ceil(129/17)
#define NBLK      1024          // persistent blocks (4/CU); 4 regions each
#define NREG      (NP / 256 / NBLK)   // = 4

typedef float    f32x2 __attribute__((ext_vector_type(2)));
typedef float    f32x4 __attribute__((ext_vector_type(4)));
typedef _Float16 f16x2 __attribute__((ext_vector_type(2)));

// fp16 table: 6321 rows x 104 B = 0.66 MB. fp16 abs err ~1.5e-3 + 2e-3
// interp << 1.02e-2 threshold (measured absmax 1.95e-3, stable R5-R6).
__device__ __align__(16) _Float16 g_table[NSAMP * ROWSTRIDE];

// ---------------------------------------------------------------------------
// build_table: block = (bucket, 17-sample chunk), 392 blocks. (~4 us total;
// audit shows erf cost is ~34 wave-instrs/block -> not worth more surgery.)
// ---------------------------------------------------------------------------
__global__ __launch_bounds__(256) void build_table(
    const float* __restrict__ embd,
    const float* __restrict__ w1,
    const float* __restrict__ b1,
    const float* __restrict__ w2,
    const float* __restrict__ b2)
{
    const int blk = blockIdx.x;
    const int t   = threadIdx.x;
    const int bu  = blk >> 3;               // bucket
    const int ch  = blk & 7;                // chunk

    __shared__ union U {
        float w1s[HID * HID];                                     // 40804 B (phase 0)
        struct { float w2s[OD * 104]; float hs[CHUNK * 104]; } p; // 27872 B (A/B)
    } u;
    __shared__ float zc[224];               // z0 at [0..100], c at [112..212]

    for (int i = t; i < HID * HID; i += 256) u.w1s[i] = w1[i];
    __syncthreads();

    if (t < HID) {                          // affine z(dist) = z0 + dist*c
        const float* __restrict__ r  = u.w1s + t * HID;   // stride 101 = 5 mod 32: conflict-free
        const float* __restrict__ ea = embd + (bu + 1) * ED;  // wave-uniform -> scalar loads
        float acc = b1[t];
        #pragma unroll 10
        for (int kk = 0; kk < ED; kk++)
            acc = fmaf(ea[kk], r[kk], fmaf(ea[ED + kk], r[ED + kk], acc));
        zc[t]       = acc;
        zc[112 + t] = r[2 * ED];
    }
    __syncthreads();                        // w1s reads done; reuse region

    for (int i = t; i < OD * HID; i += 256) {
        const int o = i / HID, j = i - o * HID;
        u.p.w2s[o * 104 + j] = w2[i];
    }

    #pragma unroll
    for (int si = 0; si < CHUNK; si++) {
        const int k = ch * CHUNK + si;
        if (t < HID && k < K) {
            const float dist = (float)k * (1.0f / 128.0f);
            const float z = fmaf(dist, zc[112 + t], zc[t]);
            u.p.hs[si * 104 + t] = 0.5f * z * (1.0f + erff(z * 0.70710678118654752f));
        }
    }
    __syncthreads();

    for (int d = t; d < CHUNK * OD; d += 256) {
        const int si = d / OD, o = d - si * OD;
        const int k = ch * CHUNK + si;
        if (k >= K) continue;
        float acc = b2[o];
        const float4* __restrict__ h4 = (const float4*)(u.p.hs  + si * 104);
        const float4* __restrict__ w4 = (const float4*)(u.p.w2s + o  * 104);
        #pragma unroll
        for (int jj = 0; jj < 25; jj++) {
            const float4 hh = h4[jj], ww = w4[jj];
            acc = fmaf(hh.x, ww.x, acc);
            acc = fmaf(hh.y, ww.y, acc);
            acc = fmaf(hh.z, ww.z, acc);
            acc = fmaf(hh.w, ww.w, acc);
        }
        acc = fmaf(u.p.hs[si * 104 + 100], u.p.w2s[o * 104 + 100], acc);
        g_table[(bu * K + k) * ROWSTRIDE + o] = (_Float16)acc;
    }
}

// ---------------------------------------------------------------------------
// half_val: one f32x2 (two output floats) for a point, from its packed pk.
// In-range (pk.x>=0): two f16x2 gathers + f32 lerp. OOB: exact f32 from LDS.
// ---------------------------------------------------------------------------
__device__ __forceinline__ f32x2 half_val(const int4 pk, int c2,
                                          const f16x2* __restrict__ tabh,
                                          const f32x2* sTail)
{
    f32x2 r;
    if (pk.x >= 0) {
        const float fr = __int_as_float(pk.z);
        const f16x2 a = tabh[pk.x + c2];
        const f16x2 b = tabh[pk.y + c2];
        const float ax = (float)a.x, ay = (float)a.y;
        r.x = fmaf(fr, (float)b.x - ax, ax);
        r.y = fmaf(fr, (float)b.y - ay, ay);
    } else {
        r = sTail[c2 - pk.x - 1];           // sel(0|25) + c2
    }
    return r;
}

// ---------------------------------------------------------------------------
// main: 1024 persistent blocks x 4 regions of 256 points.
// Per region: phase 1 (searchsorted -> s_pk[256], one point/thread), then
// phase 2: 3200 f32x4 output slots (12.5 iters of 256). Each non-boundary
// slot = 2 adjacent f32x2 halves of ONE point -> 1 pk ds_read_b128 +
// 4 dword gathers + 1 dwordx4 store per 16 B (halves the LDS-read and
// store-instruction count vs the f32x2 loop). Boundary slots (1 in 25)
// span two points and read two pks.
// ---------------------------------------------------------------------------
__global__ __launch_bounds__(256) void embed_main(
    const float* __restrict__ x,
    const float* __restrict__ boundaries,
    const float* __restrict__ embd_oob,
    float* __restrict__ out)
{
    __shared__ float sB[NB];
    __shared__ f32x2 sTail[50];             // oob row0 at [0..25), row1 at [25..50)
    __shared__ int4  s_pk[256];             // {r0, r1, frac_bits, pad}
    const int t = threadIdx.x;
    if (t < NB) sB[t] = boundaries[t];
    if (t < 2 * OD) ((float*)sTail)[t] = embd_oob[t];

    const f16x2* __restrict__ tabh = (const f16x2*)g_table;  // 26 f16x2/row

    for (int reg = 0; reg < NREG; reg++) {
        const int pbase = (reg * NBLK + blockIdx.x) * 256;   // contiguous sweep
        __syncthreads();                    // sTail ready / s_pk reusable

        // ---- phase 1: one point per thread ----
        const float xv = x[pbase + t];
        int   r0, r1;
        float frac = 0.0f;
        if (xv <= sB[0]) {                  // idx == 0  -> embd_oob[0]
            r0 = -1;  r1 = -1;
        } else if (xv > sB[NB - 1]) {       // idx == 50 -> embd_oob[1]
            r0 = -26; r1 = -26;
        } else {
            // linspace guess + 2-compare fixup = exact searchsorted 'left'
            int j = (int)(xv * 49.0f);
            if (j > 48) j = 48;
            const int idx = (xv > sB[j]) ? ((xv > sB[j + 1]) ? j + 2 : j + 1) : j;
            const float lo = sB[idx - 1];
            const float hi = sB[idx];
            const float dist = (xv - lo) / (hi - lo);   // same expr as reference
            const float tt = dist * 128.0f;             // dist in (0,1]
            int k0 = (int)tt;
            if (k0 > 127) k0 = 127;                     // dist==1 -> k0=127,frac=1
            frac = tt - (float)k0;
            const int row = (idx - 1) * K + k0;         // row+1 <= NSAMP-1
            r0 = row * 26; r1 = r0 + 26;                // f16x2 units
        }
        s_pk[t] = make_int4(r0, r1, __float_as_int(frac), 0);
        __syncthreads();

        // ---- phase 2: f32x4 stores over the region's 12800 floats ----
        f32x4* __restrict__ o4 = (f32x4*)(out + (size_t)pbase * OD);

        #pragma unroll
        for (int it = 0; it < 12; it++) {
            const int e4 = it * 256 + t;    // f32x4 slot 0..3071
            const int f  = 4 * e4;
            const int pt = f / 50;          // point in region (magic mul)
            const int c  = f - 50 * pt;     // even, 0..48
            const int cA = c >> 1;          // f32x2 half index 0..24
            const int4 pkA = s_pk[pt];
            const f32x2 rA = half_val(pkA, cA, tabh, sTail);
            f32x2 rB;
            if (c < 48) rB = half_val(pkA, cA + 1, tabh, sTail);
            else        rB = half_val(s_pk[pt + 1], 0, tabh, sTail);
            f32x4 v; v.x = rA.x; v.y = rA.y; v.z = rB.x; v.w = rB.y;
            o4[e4] = v;
        }
        if (t < 128) {                      // tail: slots 3072..3199
            const int e4 = 12 * 256 + t;
            const int f  = 4 * e4;
            const int pt = f / 50;
            const int c  = f - 50 * pt;
            const int cA = c >> 1;
            const int4 pkA = s_pk[pt];
            const f32x2 rA = half_val(pkA, cA, tabh, sTail);
            f32x2 rB;
            if (c < 48) rB = half_val(pkA, cA + 1, tabh, sTail);
            else        rB = half_val(s_pk[pt + 1], 0, tabh, sTail);
            f32x4 v; v.x = rA.x; v.y = rA.y; v.z = rB.x; v.w = rB.y;
            o4[e4] = v;
        }
    }
}

extern "C" void kernel_launch(void* const* d_in, const int* in_sizes, int n_in,
                              void* d_out, int out_size, void* d_ws, size_t ws_size,
                              hipStream_t stream) {
    const float* x    = (const float*)d_in[0];
    const float* bnd  = (const float*)d_in[1];
    const float* embd = (const float*)d_in[2];
    const float* oob  = (const float*)d_in[3];
    const float* w1   = (const float*)d_in[4];
    const float* b1   = (const float*)d_in[5];
    const float* w2   = (const float*)d_in[6];
    const float* b2   = (const float*)d_in[7];
    float* out = (float*)d_out;

    build_table<<<NBUCKET * NCHUNK, 256, 0, stream>>>(embd, w1, b1, w2, b2);
    embed_main<<<NBLK, 256, 0, stream>>>(x, bnd, oob, out);
}

// Round 8
// 237.698 us; speedup vs baseline: 1.0947x; 1.0947x over previous
//
#include <hip/hip_runtime.h>
#include <math.h>

#define NB        50            // n_boundaries
#define ED        50            // EMBD_DIM
#define OD        50            // OUT_DIM
#define HID       101           // MLP width
#define K         129           // dist samples per bucket (128 intervals)
#define NBUCKET   49            // in-range buckets (idx in [1,49])
#define NSAMP     (NBUCKET * K) // 6321 in-range rows
#define NROWS     (NSAMP + 2)   // + oob0, oob1 rows (branch-free hot loop)
#define ROWSTRIDE 52            // halves per row, 104 B = dword-aligned
#define NP        (16 * 65536)  // B*N points
#define CHUNK     17            // samples per build block
#define NCHUNK    8             // ceil(129/17)

typedef float    f32x2 __attribute__((ext_vector_type(2)));
typedef _Float16 f16x2 __attribute__((ext_vector_type(2)));

// fp16 table: 6323 rows x 104 B = 0.66 MB. fp16 + interp err ~2e-3
// << 1.02e-2 threshold (measured absmax 1.95e-3, stable R5-R7).
// OOB rows are fp16 too now (adds ~1.5e-4 on 66% of points) so the hot
// loop is completely branch-free: R7 showed the two-path exec-masked loop
// costs more than it saves (67% of waves straddle in-range/OOB points).
__device__ __align__(16) _Float16 g_table[NROWS * ROWSTRIDE];

// ---------------------------------------------------------------------------
// build_table: block = (bucket, 17-sample chunk), 392 blocks + 1 oob block.
// Phase 0: stage w1 in LDS (coalesced; strided reads 101 = 5 mod 32 are
//          conflict-free), compute affine z(dist) = z0 + dist*c.
// Phase A: h[si][j] = gelu_exact(z) into LDS (stride 104).
// Phase B: table[s][o] = (fp16)(b2[o] + w2[o,:] @ h[si,:]), float4 LDS reads.
// ---------------------------------------------------------------------------
__global__ __launch_bounds__(256) void build_table(
    const float* __restrict__ embd,
    const float* __restrict__ embd_oob,
    const float* __restrict__ w1,
    const float* __restrict__ b1,
    const float* __restrict__ w2,
    const float* __restrict__ b2)
{
    const int blk = blockIdx.x;
    const int t   = threadIdx.x;

    if (blk == NBUCKET * NCHUNK) {          // oob rows -> fp16 copy
        if (t < 2 * OD) {
            const int which = t / OD, o = t - which * OD;
            g_table[(NSAMP + which) * ROWSTRIDE + o] = (_Float16)embd_oob[t];
        }
        return;
    }

    const int bu = blk >> 3;                // bucket
    const int ch = blk & 7;                 // chunk

    __shared__ union U {
        float w1s[HID * HID];                                     // 40804 B (phase 0)
        struct { float w2s[OD * 104]; float hs[CHUNK * 104]; } p; // 27872 B (A/B)
    } u;
    __shared__ float zc[224];               // z0 at [0..100], c at [112..212]

    for (int i = t; i < HID * HID; i += 256) u.w1s[i] = w1[i];
    __syncthreads();

    if (t < HID) {                          // affine z(dist) = z0 + dist*c
        const float* __restrict__ r  = u.w1s + t * HID;
        const float* __restrict__ ea = embd + (bu + 1) * ED;  // wave-uniform -> scalar loads
        float acc = b1[t];
        #pragma unroll 10
        for (int kk = 0; kk < ED; kk++)
            acc = fmaf(ea[kk], r[kk], fmaf(ea[ED + kk], r[ED + kk], acc));
        zc[t]       = acc;
        zc[112 + t] = r[2 * ED];
    }
    __syncthreads();                        // w1s reads done; reuse region

    for (int i = t; i < OD * HID; i += 256) {
        const int o = i / HID, j = i - o * HID;
        u.p.w2s[o * 104 + j] = w2[i];
    }

    #pragma unroll
    for (int si = 0; si < CHUNK; si++) {
        const int k = ch * CHUNK + si;
        if (t < HID && k < K) {
            const float dist = (float)k * (1.0f / 128.0f);
            const float z = fmaf(dist, zc[112 + t], zc[t]);
            u.p.hs[si * 104 + t] = 0.5f * z * (1.0f + erff(z * 0.70710678118654752f));
        }
    }
    __syncthreads();

    for (int d = t; d < CHUNK * OD; d += 256) {
        const int si = d / OD, o = d - si * OD;
        const int k = ch * CHUNK + si;
        if (k >= K) continue;
        float acc = b2[o];
        const float4* __restrict__ h4 = (const float4*)(u.p.hs  + si * 104);
        const float4* __restrict__ w4 = (const float4*)(u.p.w2s + o  * 104);
        #pragma unroll
        for (int jj = 0; jj < 25; jj++) {
            const float4 hh = h4[jj], ww = w4[jj];
            acc = fmaf(hh.x, ww.x, acc);
            acc = fmaf(hh.y, ww.y, acc);
            acc = fmaf(hh.z, ww.z, acc);
            acc = fmaf(hh.w, ww.w, acc);
        }
        acc = fmaf(u.p.hs[si * 104 + 100], u.p.w2s[o * 104 + 100], acc);
        g_table[(bu * K + k) * ROWSTRIDE + o] = (_Float16)acc;
    }
}

// ---------------------------------------------------------------------------
// main: block = 256 points (4096 blocks; R6 structure — R7's persistent
// variant regressed).
// Phase 1: per-thread searchsorted -> {r0, r1, frac} packed in one int4.
//          OOB points map to table rows NSAMP/NSAMP+1 with r1 = r0, frac = 0.
// Phase 2: branch-free: every lane does 1 ds_read_b128 + 2 f16x2 gathers +
//          f32 lerp + f32x2 store, fully coalesced (512 B/wave). OOB rows
//          are L1-resident (66% of gathers hit them).
// ---------------------------------------------------------------------------
__global__ __launch_bounds__(256) void embed_main(
    const float* __restrict__ x,
    const float* __restrict__ boundaries,
    float* __restrict__ out)
{
    __shared__ float sB[NB];
    __shared__ int4  s_pk[256];             // {r0, r1, frac_bits, pad}
    const int t = threadIdx.x;
    if (t < NB) sB[t] = boundaries[t];
    __syncthreads();

    const int p = blockIdx.x * 256 + t;
    const float xv = x[p];

    int   row, row1;
    float frac = 0.0f;
    if (xv <= sB[0]) {                      // idx == 0  -> embd_oob[0]
        row = NSAMP;     row1 = NSAMP;
    } else if (xv > sB[NB - 1]) {           // idx == 50 -> embd_oob[1]
        row = NSAMP + 1; row1 = NSAMP + 1;
    } else {
        // linspace guess + 2-compare fixup = exact searchsorted 'left'
        int j = (int)(xv * 49.0f);
        if (j > 48) j = 48;
        const int idx = (xv > sB[j]) ? ((xv > sB[j + 1]) ? j + 2 : j + 1) : j;
        const float lo = sB[idx - 1];
        const float hi = sB[idx];
        const float dist = (xv - lo) / (hi - lo);   // same expr as reference
        const float tt = dist * 128.0f;             // dist in (0,1]
        int k0 = (int)tt;
        if (k0 > 127) k0 = 127;                     // dist==1 -> k0=127,frac=1
        frac = tt - (float)k0;
        row  = (idx - 1) * K + k0;                  // row+1 <= NSAMP-1
        row1 = row + 1;
    }
    s_pk[t] = make_int4(row * 26, row1 * 26, __float_as_int(frac), 0);
    __syncthreads();

    const f16x2* __restrict__ tabh = (const f16x2*)g_table;  // 26 f16x2/row
    f32x2* __restrict__ o2 = (f32x2*)out + (size_t)blockIdx.x * 6400;

    #pragma unroll
    for (int i = 0; i < 25; i++) {
        const int e  = i * 256 + t;         // f32x2 index in block region
        const int pt = e / 25;              // point within block (magic mul)
        const int c2 = e - pt * 25;         // component 0..24
        const int4 pk = s_pk[pt];           // one ds_read_b128
        const float fr = __int_as_float(pk.z);
        const f16x2 a = tabh[pk.x + c2];
        const f16x2 b = tabh[pk.y + c2];
        const float ax = (float)a.x, ay = (float)a.y;
        f32x2 r;
        r.x = fmaf(fr, (float)b.x - ax, ax);
        r.y = fmaf(fr, (float)b.y - ay, ay);
        o2[e] = r;
    }
}

extern "C" void kernel_launch(void* const* d_in, const int* in_sizes, int n_in,
                              void* d_out, int out_size, void* d_ws, size_t ws_size,
                              hipStream_t stream) {
    const float* x    = (const float*)d_in[0];
    const float* bnd  = (const float*)d_in[1];
    const float* embd = (const float*)d_in[2];
    const float* oob  = (const float*)d_in[3];
    const float* w1   = (const float*)d_in[4];
    const float* b1   = (const float*)d_in[5];
    const float* w2   = (const float*)d_in[6];
    const float* b2   = (const float*)d_in[7];
    float* out = (float*)d_out;

    build_table<<<NBUCKET * NCHUNK + 1, 256, 0, stream>>>(embd, oob, w1, b1, w2, b2);
    embed_main<<<NP / 256, 256, 0, stream>>>(x, bnd, out);
}